// Round 2
// baseline (498.597 us; speedup 1.0000x reference)
//
#include <hip/hip_runtime.h>

#define N_NODES 100000
#define N_EDGES 3200000
#define N_FEAT  256
#define N_HID   64

// ---------------------------------------------------------------------------
// Kernel 1: W_comb[f] = sum_k W_gnn[f,k] * W_cls[k];  bias_y = b_gnn.W_cls + b_cls
// ---------------------------------------------------------------------------
__global__ void k_wcomb(const float* __restrict__ Wg, const float* __restrict__ bg,
                        const float* __restrict__ Wc, const float* __restrict__ bc,
                        float* __restrict__ wcomb, float* __restrict__ biasy) {
    int f = threadIdx.x;  // 256 threads, one per input feature
    float s = 0.f;
#pragma unroll
    for (int k = 0; k < N_HID; ++k) s += Wg[f * N_HID + k] * Wc[k];
    wcomb[f] = s;
    if (f == 0) {
        float b = 0.f;
        for (int k = 0; k < N_HID; ++k) b += bg[k] * Wc[k];
        *biasy = b + bc[0];
    }
}

// ---------------------------------------------------------------------------
// Kernel 2: in-degree over targets, 4 edges/thread (self-loop added as +1 later)
// ---------------------------------------------------------------------------
__global__ __launch_bounds__(256) void k_deg(const int4* __restrict__ col4,
                                             int* __restrict__ deg) {
    int i = blockIdx.x * blockDim.x + threadIdx.x;
    if (i >= N_EDGES / 4) return;
    int4 c = col4[i];
    atomicAdd(&deg[c.x], 1);
    atomicAdd(&deg[c.y], 1);
    atomicAdd(&deg[c.z], 1);
    atomicAdd(&deg[c.w], 1);
}

// ---------------------------------------------------------------------------
// Kernel 3: wave-per-node dual dot product.
//   p = x[i].W_est, q = x[i].W_comb
//   dinv[i]  = rsqrt(deg+1)
//   table[i] = {dinv*q, dinv*p}      (gather table for edge pass)
//   acc[i]   = table[i]              (self-loop term pre-added)
// ---------------------------------------------------------------------------
__global__ __launch_bounds__(256) void k_pqtable(
        const float* __restrict__ x, const float* __restrict__ West,
        const float* __restrict__ wcomb, const int* __restrict__ deg,
        float* __restrict__ dinv, float2* __restrict__ table,
        float2* __restrict__ acc) {
    int node = (blockIdx.x * blockDim.x + threadIdx.x) >> 6;
    int lane = threadIdx.x & 63;
    if (node >= N_NODES) return;

    float4 v  = ((const float4*)(x + (size_t)node * N_FEAT))[lane];
    float4 we = ((const float4*)West)[lane];
    float4 wc = ((const float4*)wcomb)[lane];

    float ps = v.x * we.x + v.y * we.y + v.z * we.z + v.w * we.w;
    float qs = v.x * wc.x + v.y * wc.y + v.z * wc.z + v.w * wc.w;

#pragma unroll
    for (int off = 32; off > 0; off >>= 1) {
        ps += __shfl_down(ps, off);
        qs += __shfl_down(qs, off);
    }
    if (lane == 0) {
        float di = rsqrtf((float)(deg[node] + 1));
        float2 t = make_float2(di * qs, di * ps);  // .x = y-path, .y = s-path
        dinv[node]  = di;
        table[node] = t;
        acc[node]   = t;
    }
}

// ---------------------------------------------------------------------------
// Kernel 4: per-edge gather + scatter-add, 4 edges/thread.
//   acc[c] += table[r]   via native HW fp32 atomics (unsafeAtomicAdd ->
//   global_atomic_add_f32, no CAS loop).  dinv[c] applied in finalize.
// ---------------------------------------------------------------------------
__global__ __launch_bounds__(256) void k_edge(const int4* __restrict__ row4,
                                              const int4* __restrict__ col4,
                                              const float2* __restrict__ table,
                                              float2* __restrict__ acc) {
    int i = blockIdx.x * blockDim.x + threadIdx.x;
    if (i >= N_EDGES / 4) return;
    int4 r = row4[i];
    int4 c = col4[i];
    float2 t0 = table[r.x];
    float2 t1 = table[r.y];
    float2 t2 = table[r.z];
    float2 t3 = table[r.w];
    unsafeAtomicAdd(&acc[c.x].x, t0.x);
    unsafeAtomicAdd(&acc[c.x].y, t0.y);
    unsafeAtomicAdd(&acc[c.y].x, t1.x);
    unsafeAtomicAdd(&acc[c.y].y, t1.y);
    unsafeAtomicAdd(&acc[c.z].x, t2.x);
    unsafeAtomicAdd(&acc[c.z].y, t2.y);
    unsafeAtomicAdd(&acc[c.w].x, t3.x);
    unsafeAtomicAdd(&acc[c.w].y, t3.y);
}

// ---------------------------------------------------------------------------
// Kernel 5: finalize.  y = dinv*acc.x + bias_y ; s = dinv*acc.y + b_est
// d_out layout: [y (N floats)] [s (N floats)]  (reference returns (y, s))
// ---------------------------------------------------------------------------
__global__ __launch_bounds__(256) void k_fin(
        const float* __restrict__ dinv, const float2* __restrict__ acc,
        const float* __restrict__ biasy, const float* __restrict__ best,
        float* __restrict__ out) {
    int i = blockIdx.x * blockDim.x + threadIdx.x;
    if (i >= N_NODES) return;
    float di = dinv[i];
    float2 a = acc[i];
    out[i]           = di * a.x + biasy[0];
    out[N_NODES + i] = di * a.y + best[0];
}

extern "C" void kernel_launch(void* const* d_in, const int* in_sizes, int n_in,
                              void* d_out, int out_size, void* d_ws, size_t ws_size,
                              hipStream_t stream) {
    const int*   ei   = (const int*)d_in[0];    // [2, E] row-major: [0:E]=src, [E:2E]=dst
    const float* x    = (const float*)d_in[1];  // [N, 256]
    const float* West = (const float*)d_in[2];  // [256, 1]
    const float* best = (const float*)d_in[3];  // [1]
    const float* Wg   = (const float*)d_in[4];  // [256, 64]
    const float* bg   = (const float*)d_in[5];  // [64]
    const float* Wc   = (const float*)d_in[6];  // [64, 1]
    const float* bc   = (const float*)d_in[7];  // [1]
    float* out = (float*)d_out;

    // workspace layout (all offsets 8B-aligned)
    float*  wcomb = (float*)d_ws;              // 256 f
    float*  biasy = wcomb + 256;               // 1 f
    int*    deg   = (int*)(wcomb + 512);       // N i32
    float*  dinv  = (float*)(deg + N_NODES);   // N f
    float2* table = (float2*)(dinv + N_NODES); // N f2
    float2* acc   = table + N_NODES;           // N f2

    hipMemsetAsync(deg, 0, N_NODES * sizeof(int), stream);
    k_wcomb<<<1, 256, 0, stream>>>(Wg, bg, Wc, bc, wcomb, biasy);
    k_deg<<<(N_EDGES / 4 + 255) / 256, 256, 0, stream>>>(
        (const int4*)(ei + N_EDGES), deg);
    k_pqtable<<<(N_NODES * 64 + 255) / 256, 256, 0, stream>>>(x, West, wcomb, deg,
                                                              dinv, table, acc);
    k_edge<<<(N_EDGES / 4 + 255) / 256, 256, 0, stream>>>(
        (const int4*)ei, (const int4*)(ei + N_EDGES), table, acc);
    k_fin<<<(N_NODES + 255) / 256, 256, 0, stream>>>(dinv, acc, biasy, best, out);
}

// Round 3
// 130.922 us; speedup vs baseline: 3.8083x; 3.8083x over previous
//
#include <hip/hip_runtime.h>

#define N_NODES 100000
#define N_EDGES 3200000
#define N_FEAT  256
#define N_HID   64

// ---- bin partition geometry ----
#define BIN_SHIFT 9
#define BIN_W     512                       // target-nodes per bin
#define NBINS     196                       // ceil(N_NODES / BIN_W)
#define BIN_CAP   17408                     // mean 16384, sigma ~128 -> +8 sigma
#define NPART     512                       // partition blocks
#define EPB       ((N_EDGES + NPART - 1) / NPART)   // 6250 edges per partition block

// ---------------------------------------------------------------------------
// W_comb[f] = sum_k W_gnn[f,k]*W_cls[k];  bias_y = b_gnn.W_cls + b_cls
// ---------------------------------------------------------------------------
__global__ void k_wcomb(const float* __restrict__ Wg, const float* __restrict__ bg,
                        const float* __restrict__ Wc, const float* __restrict__ bc,
                        float* __restrict__ wcomb, float* __restrict__ biasy) {
    int f = threadIdx.x;
    float s = 0.f;
#pragma unroll
    for (int k = 0; k < N_HID; ++k) s += Wg[f * N_HID + k] * Wc[k];
    wcomb[f] = s;
    if (f == 0) {
        float b = 0.f;
        for (int k = 0; k < N_HID; ++k) b += bg[k] * Wc[k];
        *biasy = b + bc[0];
    }
}

// ---------------------------------------------------------------------------
// Wave-per-node dual dot product: pq[i] = { x[i].W_comb, x[i].W_est }
// ---------------------------------------------------------------------------
__global__ __launch_bounds__(256) void k_pq(const float* __restrict__ x,
                                            const float* __restrict__ West,
                                            const float* __restrict__ wcomb,
                                            float2* __restrict__ pq) {
    int node = (blockIdx.x * blockDim.x + threadIdx.x) >> 6;
    int lane = threadIdx.x & 63;
    if (node >= N_NODES) return;
    float4 v  = ((const float4*)(x + (size_t)node * N_FEAT))[lane];
    float4 we = ((const float4*)West)[lane];
    float4 wc = ((const float4*)wcomb)[lane];
    float ps = v.x * we.x + v.y * we.y + v.z * we.z + v.w * we.w;
    float qs = v.x * wc.x + v.y * wc.y + v.z * wc.z + v.w * wc.w;
#pragma unroll
    for (int off = 32; off > 0; off >>= 1) {
        ps += __shfl_down(ps, off);
        qs += __shfl_down(qs, off);
    }
    if (lane == 0) pq[node] = make_float2(qs, ps);   // .x = y-path, .y = s-path
}

// ---------------------------------------------------------------------------
// Partition: scatter edges into per-target-bin regions.
// packed word = (local_target << 17) | src   (src < 2^17, local < 512)
// Global atomics: one reservation per (block,bin) -- ~100k, not 3.2M.
// ---------------------------------------------------------------------------
__global__ __launch_bounds__(256) void k_part(const int* __restrict__ row,
                                              const int* __restrict__ col,
                                              int* __restrict__ cursor,
                                              unsigned int* __restrict__ grouped) {
    __shared__ int hist[NBINS];
    __shared__ int base[NBINS];
    int tid = threadIdx.x;
    for (int i = tid; i < NBINS; i += 256) hist[i] = 0;
    __syncthreads();
    int e0 = blockIdx.x * EPB;
    int e1 = e0 + EPB;
    if (e1 > N_EDGES) e1 = N_EDGES;
    for (int e = e0 + tid; e < e1; e += 256)
        atomicAdd(&hist[col[e] >> BIN_SHIFT], 1);
    __syncthreads();
    for (int i = tid; i < NBINS; i += 256) {
        int c = hist[i];
        base[i] = c ? atomicAdd(&cursor[i], c) : 0;
        hist[i] = 0;
    }
    __syncthreads();
    for (int e = e0 + tid; e < e1; e += 256) {
        int c = col[e];
        int b = c >> BIN_SHIFT;
        int slot = base[b] + atomicAdd(&hist[b], 1);
        if (slot < BIN_CAP)   // statistically impossible overflow; protect ws
            grouped[(size_t)b * BIN_CAP + slot] =
                ((unsigned)(c & (BIN_W - 1)) << 17) | (unsigned)row[e];
    }
}

// ---------------------------------------------------------------------------
// Per-bin degree histogram (LDS) -> dinv, table = dinv * pq
// ---------------------------------------------------------------------------
__global__ __launch_bounds__(256) void k_bindeg(const int* __restrict__ cursor,
                                                const unsigned int* __restrict__ grouped,
                                                const float2* __restrict__ pq,
                                                float* __restrict__ dinv,
                                                float2* __restrict__ table) {
    __shared__ int dh[BIN_W];
    int b = blockIdx.x, tid = threadIdx.x;
    for (int i = tid; i < BIN_W; i += 256) dh[i] = 0;
    __syncthreads();
    int cnt = cursor[b];
    if (cnt > BIN_CAP) cnt = BIN_CAP;
    const unsigned int* g = grouped + (size_t)b * BIN_CAP;
    for (int i = tid; i < cnt; i += 256) atomicAdd(&dh[g[i] >> 17], 1);
    __syncthreads();
    for (int l = tid; l < BIN_W; l += 256) {
        int node = b * BIN_W + l;
        if (node < N_NODES) {
            float di = rsqrtf((float)(dh[l] + 1));   // +1 self-loop
            dinv[node] = di;
            float2 v = pq[node];
            table[node] = make_float2(di * v.x, di * v.y);
        }
    }
}

// ---------------------------------------------------------------------------
// Per-bin accumulate: 4KB LDS tile, ds_add_f32 atomics (on-CU, no fabric),
// self-loop pre-added, finalize fused (out = dinv*tile + bias).
// ---------------------------------------------------------------------------
__global__ __launch_bounds__(1024) void k_binacc(const int* __restrict__ cursor,
                                                 const unsigned int* __restrict__ grouped,
                                                 const float2* __restrict__ table,
                                                 const float* __restrict__ dinv,
                                                 const float* __restrict__ biasy,
                                                 const float* __restrict__ best,
                                                 float* __restrict__ out) {
    __shared__ float2 tile[BIN_W];
    int b = blockIdx.x, tid = threadIdx.x;
    for (int l = tid; l < BIN_W; l += 1024) {
        int node = b * BIN_W + l;
        tile[l] = (node < N_NODES) ? table[node] : make_float2(0.f, 0.f);
    }
    __syncthreads();
    int cnt = cursor[b];
    if (cnt > BIN_CAP) cnt = BIN_CAP;
    const unsigned int* g = grouped + (size_t)b * BIN_CAP;
    for (int i = tid; i < cnt; i += 1024) {
        unsigned int v = g[i];
        float2 t = table[v & 0x1FFFFu];
        int lc = v >> 17;
        atomicAdd(&tile[lc].x, t.x);
        atomicAdd(&tile[lc].y, t.y);
    }
    __syncthreads();
    float by = biasy[0], bs = best[0];
    for (int l = tid; l < BIN_W; l += 1024) {
        int node = b * BIN_W + l;
        if (node < N_NODES) {
            float di = dinv[node];
            out[node]           = di * tile[l].x + by;
            out[N_NODES + node] = di * tile[l].y + bs;
        }
    }
}

// ===========================================================================
// Fallback pipeline (proven, ~500us) used only if ws_size is too small.
// ===========================================================================
__global__ __launch_bounds__(256) void k_deg_fb(const int* __restrict__ col,
                                                int* __restrict__ deg) {
    int e = blockIdx.x * blockDim.x + threadIdx.x;
    if (e < N_EDGES) atomicAdd(&deg[col[e]], 1);
}
__global__ __launch_bounds__(256) void k_pqtable_fb(
        const float* __restrict__ x, const float* __restrict__ West,
        const float* __restrict__ wcomb, const int* __restrict__ deg,
        float* __restrict__ dinv, float2* __restrict__ table,
        float2* __restrict__ acc) {
    int node = (blockIdx.x * blockDim.x + threadIdx.x) >> 6;
    int lane = threadIdx.x & 63;
    if (node >= N_NODES) return;
    float4 v  = ((const float4*)(x + (size_t)node * N_FEAT))[lane];
    float4 we = ((const float4*)West)[lane];
    float4 wc = ((const float4*)wcomb)[lane];
    float ps = v.x * we.x + v.y * we.y + v.z * we.z + v.w * we.w;
    float qs = v.x * wc.x + v.y * wc.y + v.z * wc.z + v.w * wc.w;
#pragma unroll
    for (int off = 32; off > 0; off >>= 1) {
        ps += __shfl_down(ps, off);
        qs += __shfl_down(qs, off);
    }
    if (lane == 0) {
        float di = rsqrtf((float)(deg[node] + 1));
        float2 t = make_float2(di * qs, di * ps);
        dinv[node] = di; table[node] = t; acc[node] = t;
    }
}
__global__ __launch_bounds__(256) void k_edge_fb(const int* __restrict__ ei,
                                                 const float2* __restrict__ table,
                                                 float2* __restrict__ acc) {
    int e = blockIdx.x * blockDim.x + threadIdx.x;
    if (e >= N_EDGES) return;
    float2 t = table[ei[e]];
    int c = ei[N_EDGES + e];
    unsafeAtomicAdd(&acc[c].x, t.x);
    unsafeAtomicAdd(&acc[c].y, t.y);
}
__global__ __launch_bounds__(256) void k_fin_fb(
        const float* __restrict__ dinv, const float2* __restrict__ acc,
        const float* __restrict__ biasy, const float* __restrict__ best,
        float* __restrict__ out) {
    int i = blockIdx.x * blockDim.x + threadIdx.x;
    if (i >= N_NODES) return;
    float di = dinv[i];
    float2 a = acc[i];
    out[i]           = di * a.x + biasy[0];
    out[N_NODES + i] = di * a.y + best[0];
}

extern "C" void kernel_launch(void* const* d_in, const int* in_sizes, int n_in,
                              void* d_out, int out_size, void* d_ws, size_t ws_size,
                              hipStream_t stream) {
    const int*   ei   = (const int*)d_in[0];
    const float* x    = (const float*)d_in[1];
    const float* West = (const float*)d_in[2];
    const float* best = (const float*)d_in[3];
    const float* Wg   = (const float*)d_in[4];
    const float* bg   = (const float*)d_in[5];
    const float* Wc   = (const float*)d_in[6];
    const float* bc   = (const float*)d_in[7];
    float* out = (float*)d_out;

    // ---- workspace layout (bytes) ----
    char* ws = (char*)d_ws;
    float*  wcomb = (float*)ws;                       // 256 f          @ 0
    float*  biasy = wcomb + 256;                      // 1 f
    float2* pq    = (float2*)(ws + 2048);             // N f2  (800000 B)
    float2* table = (float2*)(ws + 802048);           // N f2  (800000 B)
    float*  dinv  = (float*)(ws + 1602048);           // N f   (400000 B)
    int*    cursor= (int*)(ws + 2002048);             // NBINS i (784 B)
    unsigned int* grouped = (unsigned int*)(ws + 2003072); // NBINS*BIN_CAP u32
    size_t need = 2003072 + (size_t)NBINS * BIN_CAP * 4;   // ~15.65 MB

    if (ws_size >= need) {
        k_wcomb<<<1, 256, 0, stream>>>(Wg, bg, Wc, bc, wcomb, biasy);
        hipMemsetAsync(cursor, 0, NBINS * sizeof(int), stream);
        k_pq<<<(N_NODES * 64 + 255) / 256, 256, 0, stream>>>(x, West, wcomb, pq);
        k_part<<<NPART, 256, 0, stream>>>(ei, ei + N_EDGES, cursor, grouped);
        k_bindeg<<<NBINS, 256, 0, stream>>>(cursor, grouped, pq, dinv, table);
        k_binacc<<<NBINS, 1024, 0, stream>>>(cursor, grouped, table, dinv,
                                             biasy, best, out);
    } else {
        // fallback: global-atomic pipeline (needs ~2.4 MB)
        int*    deg  = (int*)(ws + 2048 + 800000 * 2 + 400000);
        float2* acc  = pq;       // reuse
        float2* tbl  = table;
        hipMemsetAsync(deg, 0, N_NODES * sizeof(int), stream);
        k_wcomb<<<1, 256, 0, stream>>>(Wg, bg, Wc, bc, wcomb, biasy);
        k_deg_fb<<<(N_EDGES + 255) / 256, 256, 0, stream>>>(ei + N_EDGES, deg);
        k_pqtable_fb<<<(N_NODES * 64 + 255) / 256, 256, 0, stream>>>(
            x, West, wcomb, deg, dinv, tbl, acc);
        k_edge_fb<<<(N_EDGES + 255) / 256, 256, 0, stream>>>(ei, tbl, acc);
        k_fin_fb<<<(N_NODES + 255) / 256, 256, 0, stream>>>(dinv, acc, biasy, best, out);
    }
}